// Round 4
// baseline (87.048 us; speedup 1.0000x reference)
//
#include <hip/hip_runtime.h>

#define NN 4096
#define NT 1024
#define NCELL 64                 // 64x64 grid, cell size 8.0 (>= 2*NMS radius)
#define NCELLS 4096
#define NBUCK 4096

__global__ __launch_bounds__(NT)
void DistanceNMS_kernel(const float* __restrict__ peaks, float* __restrict__ out)
{
    // ---- LDS (~124 KB) ----
    __shared__ float px[NN];                    // 16K  by ORIGINAL index
    __shared__ float py[NN];                    // 16K
    __shared__ unsigned kb[NN];                 // 16K  ~conf_bits by orig idx
    __shared__ unsigned cellidx[NCELLS];        // 16K  count -> excl start -> end
    __shared__ unsigned buckidx[NBUCK];         // 16K  count -> excl start -> end
    __shared__ unsigned short cellpts[NN];      //  8K  orig idx grouped by cell
    __shared__ unsigned long long sortbuf[NN];  // 32K  (kb<<32)|oi
    __shared__ unsigned char state_[NN];        //  4K  0=UNDET 1=KEPT 2=DEAD
    __shared__ unsigned wavesumA[16], wavesumB[16];

    const int tid  = threadIdx.x;
    const int lane = tid & 63;
    const int wv   = tid >> 6;
    const int b    = blockIdx.x;
    const float* bp = peaks + (size_t)b * NN * 3;
    float* bo = out + (size_t)b * NN * 3;

    // ---- phase 0: zero counters ----
    {
        int t4 = tid << 2;
        cellidx[t4] = 0; cellidx[t4+1] = 0; cellidx[t4+2] = 0; cellidx[t4+3] = 0;
        buckidx[t4] = 0; buckidx[t4+1] = 0; buckidx[t4+2] = 0; buckidx[t4+3] = 0;
    }
    __syncthreads();                                           // B1

    // ---- phase 1: load + count (cells by position, buckets by conf) ----
    for (int j = tid; j < NN; j += NT) {
        float x = bp[j*3+0], y = bp[j*3+1], cf = bp[j*3+2];
        px[j] = x; py[j] = y;
        kb[j] = ~__float_as_uint(cf);          // conf>=0 -> monotone bits
        state_[j] = 0;
        int cx = min((int)(x * 0.125f), 63);
        int cy = min((int)(y * 0.125f), 63);
        atomicAdd(&cellidx[(cy << 6) | cx], 1u);
        int bk = 4095 - min((int)__fmul_rn(cf, 4096.0f), 4095);  // exact, monotone desc-conf
        atomicAdd(&buckidx[bk], 1u);
    }
    __syncthreads();                                           // B2

    // ---- phase 2: dual in-place exclusive scan (4096 each) ----
    {
        int t4 = tid << 2;
        unsigned a0=cellidx[t4], a1=cellidx[t4+1], a2=cellidx[t4+2], a3=cellidx[t4+3];
        unsigned b0=buckidx[t4], b1=buckidx[t4+1], b2=buckidx[t4+2], b3=buckidx[t4+3];
        unsigned sa = a0+a1+a2+a3, sb = b0+b1+b2+b3;
        unsigned ia = sa, ib = sb;
        for (int off = 1; off < 64; off <<= 1) {
            unsigned na = __shfl_up(ia, off);
            unsigned nb = __shfl_up(ib, off);
            if (lane >= off) { ia += na; ib += nb; }
        }
        if (lane == 63) { wavesumA[wv] = ia; wavesumB[wv] = ib; }
        __syncthreads();                                       // B3
        if (tid == 0) {
            unsigned acc = 0;
            for (int i = 0; i < 16; ++i) { unsigned t = wavesumA[i]; wavesumA[i] = acc; acc += t; }
            acc = 0;
            for (int i = 0; i < 16; ++i) { unsigned t = wavesumB[i]; wavesumB[i] = acc; acc += t; }
        }
        __syncthreads();                                       // B4
        unsigned baseA = wavesumA[wv] + (ia - sa);
        unsigned baseB = wavesumB[wv] + (ib - sb);
        cellidx[t4]=baseA; cellidx[t4+1]=baseA+a0; cellidx[t4+2]=baseA+a0+a1; cellidx[t4+3]=baseA+a0+a1+a2;
        buckidx[t4]=baseB; buckidx[t4+1]=baseB+b0; buckidx[t4+2]=baseB+b0+b1; buckidx[t4+3]=baseB+b0+b1+b2;
    }
    __syncthreads();                                           // B5

    // ---- phase 3: scatter (counters become cursors; end state = bucket/cell END) ----
    for (int j = tid; j < NN; j += NT) {
        float x = px[j], y = py[j];
        int cx = min((int)(x * 0.125f), 63);
        int cy = min((int)(y * 0.125f), 63);
        unsigned p = atomicAdd(&cellidx[(cy << 6) | cx], 1u);
        cellpts[p] = (unsigned short)j;
        unsigned kbv = kb[j];
        float cf = __uint_as_float(~kbv);
        int bk = 4095 - min((int)__fmul_rn(cf, 4096.0f), 4095);
        unsigned q = atomicAdd(&buckidx[bk], 1u);
        sortbuf[q] = ((unsigned long long)kbv << 32) | (unsigned)j;
    }
    __syncthreads();                                           // B6
    // ranges are now [c ? idx[c-1] : 0, idx[c])

    // ---- phase 4a: per-bucket insertion sort (disjoint ranges, unique u64 keys) ----
    for (int k = 0; k < 4; ++k) {
        int bkt = tid + (k << 10);
        unsigned s = bkt ? buckidx[bkt-1] : 0;
        unsigned e = buckidx[bkt];
        for (unsigned i = s + 1; i < e; ++i) {
            unsigned long long v = sortbuf[i];
            unsigned t2 = i;
            while (t2 > s && sortbuf[t2-1] > v) { sortbuf[t2] = sortbuf[t2-1]; --t2; }
            sortbuf[t2] = v;
        }
    }

    // ---- phase 4b: barrier-free spin fixpoint == exact greedy NMS ----
    // DEAD iff some earlier KEPT neighbor (d2<16); KEPT once all earlier conflicting
    // neighbors are DEAD. Monotone LDS updates, volatile reads; min undet always
    // self-resolves -> no deadlock; no barriers needed.
    volatile unsigned char* vstate = state_;
    auto eval = [&](int j) -> int {   // 0=undet 1=kept 2=dead
        float x = px[j], y = py[j];
        unsigned kj = kb[j];
        int cx = min((int)(x * 0.125f), 63);
        int cy = min((int)(y * 0.125f), 63);
        float u = __fsub_rn(x, (float)(cx << 3));   // exact (Sterbenz)
        float v = __fsub_rn(y, (float)(cy << 3));
        int cx0 = (u < 4.0f) ? max(cx - 1, 0) : cx;
        int cy0 = (v < 4.0f) ? max(cy - 1, 0) : cy;
        int cx1 = min(cx0 + 1, 63), cy1 = min(cy0 + 1, 63);
        bool any_undet = false;
        for (int cyy = cy0; cyy <= cy1; ++cyy) {
            for (int cxx = cx0; cxx <= cx1; ++cxx) {
                int c = (cyy << 6) | cxx;
                unsigned s = c ? cellidx[c-1] : 0;
                unsigned e = cellidx[c];
                for (unsigned t = s; t < e; ++t) {
                    int m = cellpts[t];
                    unsigned km = kb[m];
                    if (!(km < kj || (km == kj && m < j))) continue;   // earlier only
                    float dx  = __fsub_rn(px[m], x);
                    float dyy = __fsub_rn(py[m], y);
                    float d2  = __fadd_rn(__fmul_rn(dx, dx), __fmul_rn(dyy, dyy));
                    if (d2 < 16.0f) {
                        unsigned char st = vstate[m];
                        if (st == 1) return 2;        // state==1 is final -> safe
                        if (st == 0) any_undet = true;
                    }
                }
            }
        }
        return any_undet ? 0 : 1;
    };

    {
        unsigned remaining = 0xFu;   // each thread owns j = tid + k*1024, k=0..3
        while (remaining) {
            for (int k = 0; k < 4; ++k) {
                if (remaining & (1u << k)) {
                    int j = tid + (k << 10);
                    int r = eval(j);
                    if (r) { vstate[j] = (unsigned char)r; remaining &= ~(1u << k); }
                }
            }
        }
    }
    __syncthreads();                                           // B7

    // ---- output: sorted peaks masked by keep ----
    for (int r = tid; r < NN; r += NT) {
        unsigned long long v = sortbuf[r];
        int oi = (int)(v & 0xFFFFu);
        bool kp = (state_[oi] == 1);
        float conf = __uint_as_float(~(unsigned)(v >> 32));
        bo[r*3+0] = kp ? px[oi] : 0.0f;
        bo[r*3+1] = kp ? py[oi] : 0.0f;
        bo[r*3+2] = kp ? conf   : 0.0f;
    }
}

extern "C" void kernel_launch(void* const* d_in, const int* in_sizes, int n_in,
                              void* d_out, int out_size, void* d_ws, size_t ws_size,
                              hipStream_t stream) {
    const float* peaks = (const float*)d_in[0];
    float* out = (float*)d_out;
    const int B = in_sizes[0] / (NN * 3);
    DistanceNMS_kernel<<<B, NT, 0, stream>>>(peaks, out);
}